// Round 7
// baseline (130.970 us; speedup 1.0000x reference)
//
#include <hip/hip_runtime.h>

// ---------------------------------------------------------------------------
// MultiheadAttention (B=2, S=2048, E=1024, H=16, D=64, MAX_DIST=4, causal)
//   1. f2bf converts (x once; 4 weights fused)
//   2. proj3: kh=[bs][e], qh=[bs][e] (*0.125), vt=[e][bs]
//   3. flash attention v6: split-K uniform units, 4-wave blocks, P kept in
//      registers (shuffle redistribution, no P LDS), 35KB LDS -> 4 blocks/CU.
//      Swapped QK^T, XOR-swizzled K/V, dbuf, defer-max, cvt_pk.
//   4. combine partials -> ao
//   5. out = ao @ Wo^T -> fp32
// ---------------------------------------------------------------------------

using short8  = __attribute__((ext_vector_type(8))) short;
using floatx4 = __attribute__((ext_vector_type(4))) float;
using float4v = __attribute__((ext_vector_type(4))) float;
using ushort4v = __attribute__((ext_vector_type(4))) unsigned short;
using uint4v  = __attribute__((ext_vector_type(4))) unsigned int;

#define LOG2E 1.4426950408889634f

__device__ __forceinline__ unsigned short f2bf(float f) {
  unsigned u = __float_as_uint(f);
  return (unsigned short)((u + 0x7FFFu + ((u >> 16) & 1u)) >> 16);  // RNE
}
__device__ __forceinline__ float bf2f(unsigned short s) {
  return __uint_as_float(((unsigned)s) << 16);
}
__device__ __forceinline__ unsigned cvt_pk_bf16(float lo, float hi) {
  unsigned r;
  asm("v_cvt_pk_bf16_f32 %0, %1, %2" : "=v"(r) : "v"(lo), "v"(hi));
  return r;
}
__device__ __forceinline__ void gload_lds16(const void* g, void* l) {
  __builtin_amdgcn_global_load_lds(
      (const __attribute__((address_space(1))) unsigned int*)g,
      (__attribute__((address_space(3))) unsigned int*)l, 16, 0, 0);
}

// --------------------------- fp32 -> bf16 convert ---------------------------
__global__ void f2bf_kern(const float* __restrict__ in,
                          unsigned short* __restrict__ out, int n4) {
  int i = blockIdx.x * 256 + threadIdx.x;
  if (i >= n4) return;
  float4v v = ((const float4v*)in)[i];
  ushort4v o;
  o[0] = f2bf(v[0]); o[1] = f2bf(v[1]); o[2] = f2bf(v[2]); o[3] = f2bf(v[3]);
  ((ushort4v*)out)[i] = o;
}

__global__ void f2bfW_kern(const float* __restrict__ w0, unsigned short* o0,
                           const float* __restrict__ w1, unsigned short* o1,
                           const float* __restrict__ w2, unsigned short* o2,
                           const float* __restrict__ w3, unsigned short* o3) {
  int i = blockIdx.x * 256 + threadIdx.x;
  const float* in;
  unsigned short* out;
  switch (blockIdx.y) {
    case 0: in = w0; out = o0; break;
    case 1: in = w1; out = o1; break;
    case 2: in = w2; out = o2; break;
    default: in = w3; out = o3; break;
  }
  float4v v = ((const float4v*)in)[i];
  ushort4v o;
  o[0] = f2bf(v[0]); o[1] = f2bf(v[1]); o[2] = f2bf(v[2]); o[3] = f2bf(v[3]);
  ((ushort4v*)out)[i] = o;
}

// ------------------------------ GEMM core (NT) ------------------------------
__device__ __forceinline__ void gemm_core(
    const unsigned short* __restrict__ A, const unsigned short* __restrict__ B,
    void* __restrict__ Cv, int N, int K, int mBase, int nBase, float alpha,
    bool outbf, unsigned short* As, unsigned short* Bs) {
  const int tid = threadIdx.x;
  const int lane = tid & 63;
  const int w = tid >> 6;
  const int wr = w >> 1, wc = w & 1;
  const int lr = lane & 15, lg = lane >> 4;

  floatx4 acc[4][4] = {};

  for (int k0 = 0; k0 < K; k0 += 32) {
#pragma unroll
    for (int i = 0; i < 2; ++i) {
      int idx = i * 256 + tid;
      int row = idx >> 2, c8 = (idx & 3) * 8;
      gload_lds16(A + (size_t)(mBase + row) * K + (k0 + c8), As + idx * 8);
      gload_lds16(B + (size_t)(nBase + row) * K + (k0 + c8), Bs + idx * 8);
    }
    __syncthreads();
    short8 af[4], bfr[4];
#pragma unroll
    for (int mf = 0; mf < 4; ++mf)
      af[mf] = *(const short8*)(As + (wr * 64 + mf * 16 + lr) * 32 + lg * 8);
#pragma unroll
    for (int nf = 0; nf < 4; ++nf)
      bfr[nf] = *(const short8*)(Bs + (wc * 64 + nf * 16 + lr) * 32 + lg * 8);
#pragma unroll
    for (int mf = 0; mf < 4; ++mf)
#pragma unroll
      for (int nf = 0; nf < 4; ++nf)
        acc[mf][nf] = __builtin_amdgcn_mfma_f32_16x16x32_bf16(
            af[mf], bfr[nf], acc[mf][nf], 0, 0, 0);
    __syncthreads();
  }

#pragma unroll
  for (int mf = 0; mf < 4; ++mf)
#pragma unroll
    for (int nf = 0; nf < 4; ++nf)
#pragma unroll
      for (int r = 0; r < 4; ++r) {
        size_t row = (size_t)mBase + wr * 64 + mf * 16 + lg * 4 + r;
        size_t col = (size_t)nBase + wc * 64 + nf * 16 + lr;
        float v = acc[mf][nf][r] * alpha;
        if (outbf)
          ((unsigned short*)Cv)[row * (size_t)N + col] = f2bf(v);
        else
          ((float*)Cv)[row * (size_t)N + col] = v;
      }
}

__global__ __launch_bounds__(256, 2) void proj3_kern(
    const unsigned short* __restrict__ xbf, const unsigned short* __restrict__ wkb,
    unsigned short* __restrict__ khb,
    const unsigned short* __restrict__ wqb, unsigned short* __restrict__ qhb,
    const unsigned short* __restrict__ wvb, unsigned short* __restrict__ vtb) {
  __shared__ alignas(16) unsigned short As[128 * 32];
  __shared__ alignas(16) unsigned short Bs[128 * 32];
  int z = blockIdx.z;
  if (z == 0)
    gemm_core(xbf, wkb, khb, 1024, 1024, blockIdx.y * 128, blockIdx.x * 128,
              1.0f, true, As, Bs);
  else if (z == 1)
    gemm_core(xbf, wqb, qhb, 1024, 1024, blockIdx.y * 128, blockIdx.x * 128,
              0.125f, true, As, Bs);
  else
    gemm_core(wvb, xbf, vtb, 4096, 1024, blockIdx.x * 128, blockIdx.y * 128,
              1.0f, true, As, Bs);
}

__global__ __launch_bounds__(256, 2) void gemm_out_kern(
    const unsigned short* __restrict__ A, const unsigned short* __restrict__ B,
    float* __restrict__ C) {
  __shared__ alignas(16) unsigned short As[128 * 32];
  __shared__ alignas(16) unsigned short Bs[128 * 32];
  gemm_core(A, B, C, 1024, 1024, blockIdx.y * 128, blockIdx.x * 128, 1.0f,
            false, As, Bs);
}

// ---------------------------- flash attention v6 ----------------------------
// Split-K grid (32 hb, 48 units), LPT order (see unit decode). 4 waves, each
// owns 16 q rows. P never touches LDS: sa -> cvt_pk u32 -> 16x ds_bpermute
// redistribution -> PV A-operand. LDS 35840B -> 4 blocks/CU (16 waves/CU).
__global__ __launch_bounds__(256, 4) void attn_kern(
    const unsigned short* __restrict__ qh,   // [4096][1024], pre-scaled
    const unsigned short* __restrict__ kh,   // [4096][1024]
    const unsigned short* __restrict__ vt,   // [1024][4096]
    const float* __restrict__ pp,            // [64][9]
    unsigned short* __restrict__ ao,         // [4096][1024]
    unsigned short* __restrict__ opart,      // [1024][64][64] bf16 unnorm
    float* __restrict__ mbuf,                // [1024][64]
    float* __restrict__ lbuf) {              // [1024][64]
  __shared__ alignas(16) char smem[35840];
  unsigned short* Qs  = (unsigned short*)smem;            // 8K; later K-buf-1
  unsigned short* Vs1 = (unsigned short*)(smem + 8192);   // 8K; ppS overlay
  unsigned short* Ks0 = (unsigned short*)(smem + 16384);  // 8K
  unsigned short* Vs0 = (unsigned short*)(smem + 24576);  // 8K
  float* biasS = (float*)(smem + 32768);                  // 64*12*4 = 3K
  float* ppS   = (float*)(smem + 8192);                   // overlays Vs1

  const int tid = threadIdx.x;
  const int lane = tid & 63;
  const int w = tid >> 6;   // 0..3, owns q rows w*16..w*16+15
  const int lr = lane & 15, lg = lane >> 4;
  const int hb = blockIdx.x;
  const int h = hb & 15, b = hb >> 4;
  const int u = blockIdx.y;

  int qt, k0, k1;
  if (u == 0)       { qt = 15;     k0 = 0;  k1 = 16; }
  else if (u <= 16) { qt = 15 + u; k0 = 0;  k1 = 16; }
  else if (u == 17) { qt = 31;     k0 = 16; k1 = 32; }
  else {
    int p = (u - 18) >> 1;
    if (((u - 18) & 1) == 0) { qt = 14 - p; k0 = 0;  k1 = qt + 1; }
    else                     { qt = 30 - p; k0 = 16; k1 = qt + 1; }
  }
  const bool partial = (qt >= 16);
  const int qbase = qt * 64;
  const size_t bsQ = (size_t)b * 2048 + qbase;

  const unsigned short* khB = kh + ((size_t)b * 2048) * 1024 + h * 64;
  const unsigned short* vtB = vt + ((size_t)h * 64) * 4096 + b * 2048;

  auto stage_kv = [&](int kbase, unsigned short* Kd, unsigned short* Vd) {
#pragma unroll
    for (int i = 0; i < 2; ++i) {
      int idx = i * 256 + tid;
      int row = idx >> 3, pc = idx & 7;
      int cl = pc ^ (row & 7);  // pre-swizzled global source
      gload_lds16(khB + ((size_t)(kbase + row) << 10) + cl * 8, Kd + idx * 8);
      gload_lds16(vtB + ((size_t)row << 12) + kbase + cl * 8, Vd + idx * 8);
    }
  };

  // prologue: stage Q (linear), pp table, first K/V tile
#pragma unroll
  for (int i = 0; i < 2; ++i) {
    int idx = i * 256 + tid;
    int row = idx >> 3, c8 = (idx & 7) * 8;
    gload_lds16(qh + (bsQ + row) * 1024 + h * 64 + c8, Qs + idx * 8);
  }
  for (int idx = tid; idx < 576; idx += 256) {
    int r = idx >> 6, d = idx & 63;
    ppS[r * 64 + d] = pp[d * 9 + r];
  }
  stage_kv(k0 * 64, Ks0, Vs0);
  __syncthreads();

  // Q fragments (B-operand): lane holds Q[q = w*16+lr][d = c*32+lg*8+j]
  const int qrowL = w * 16 + lr;
  short8 aq[2];
#pragma unroll
  for (int c = 0; c < 2; ++c)
    aq[c] = *(const short8*)(Qs + qrowL * 64 + c * 32 + lg * 8);

  // rel-pos bias: biasS[row][r] = sum_d qh_scaled[row][d] * p[d][r]
  for (int idx = tid; idx < 576; idx += 256) {
    int row = idx / 9, r = idx - row * 9;
    const unsigned short* qrow = Qs + row * 64;
    const float* pr = ppS + r * 64;
    float s = 0.f;
#pragma unroll
    for (int d8 = 0; d8 < 8; ++d8) {
      short8 qv = *(const short8*)(qrow + d8 * 8);
#pragma unroll
      for (int j = 0; j < 8; ++j)
        s += bf2f((unsigned short)qv[j]) * pr[d8 * 8 + j];
    }
    biasS[row * 12 + r] = s;
  }
  __syncthreads();  // Qs/ppS prologue uses done -> both become buf-1 targets

  const int q_glob = qbase + w * 16 + lr;
  const float b8 = biasS[qrowL * 12 + 8];
  const int sl0 = lr + 16 * ((lg & 1) * 2);  // P-shuffle source lanes
  const int sl1 = sl0 + 16;

  float m_run = -1e30f, l_run = 0.f;
  floatx4 o[4] = {};

  for (int kt = k0; kt < k1; ++kt) {
    const int kbase = kt * 64;
    const int cur = (kt - k0) & 1;
    unsigned short* Kc = cur ? Qs : Ks0;
    unsigned short* Vc = cur ? Vs1 : Vs0;
    if (kt + 1 < k1)
      stage_kv(kbase + 64, cur ? Ks0 : Qs, cur ? Vs0 : Vs1);  // prefetch

    // S^T = K @ Q^T : lane holds S[k = kf*16+lg*4+r][q = w*16+lr]
    floatx4 sa[4] = {};
    __builtin_amdgcn_s_setprio(1);
#pragma unroll
    for (int kf = 0; kf < 4; ++kf)
#pragma unroll
      for (int c = 0; c < 2; ++c) {
        int row = kf * 16 + lr;
        short8 ak = *(const short8*)(Kc + row * 64 +
                                     (((c * 4 + lg) ^ (lr & 7)) * 8));
        sa[kf] = __builtin_amdgcn_mfma_f32_16x16x32_bf16(ak, aq[c], sa[kf],
                                                         0, 0, 0);
      }
    __builtin_amdgcn_s_setprio(0);

    // bias + causal mask
    float bext;
    if (qbase + w * 16 >= kbase + 67) {  // whole wave sub-tile at dist >= 4
      bext = b8;                         // folded into exp arg below
    } else {
      bext = 0.f;
#pragma unroll
      for (int kf = 0; kf < 4; ++kf)
#pragma unroll
        for (int r = 0; r < 4; ++r) {
          int dq = q_glob - (kbase + kf * 16 + lg * 4 + r);
          if (dq < 0)
            sa[kf][r] = -1e30f;
          else
            sa[kf][r] += biasS[qrowL * 12 + (dq > 4 ? 8 : dq + 4)];
        }
    }

    // online softmax with defer-max (THR=8)
    float mx = -1e30f;
#pragma unroll
    for (int kf = 0; kf < 4; ++kf)
#pragma unroll
      for (int r = 0; r < 4; ++r) mx = fmaxf(mx, sa[kf][r]);
    mx += bext;
    mx = fmaxf(mx, __shfl_xor(mx, 16, 64));
    mx = fmaxf(mx, __shfl_xor(mx, 32, 64));
    if (__any(mx > m_run + 8.f)) {
      float mn = fmaxf(m_run, mx);
      float al = __builtin_amdgcn_exp2f((m_run - mn) * LOG2E);
      m_run = mn;
      l_run *= al;
      float alo[4];
#pragma unroll
      for (int r = 0; r < 4; ++r) alo[r] = __shfl(al, lg * 4 + r, 64);
#pragma unroll
      for (int df = 0; df < 4; ++df)
#pragma unroll
        for (int r = 0; r < 4; ++r) o[df][r] *= alo[r];
    }

    // P = exp(S + bext - m), packed bf16 in registers (no LDS round-trip)
    const float c1 = (bext - m_run) * LOG2E;
    float rs = 0.f;
    unsigned pk[4][2];
#pragma unroll
    for (int kf = 0; kf < 4; ++kf) {
      float p0 = __builtin_amdgcn_exp2f(fmaf(sa[kf][0], LOG2E, c1));
      float p1 = __builtin_amdgcn_exp2f(fmaf(sa[kf][1], LOG2E, c1));
      float p2 = __builtin_amdgcn_exp2f(fmaf(sa[kf][2], LOG2E, c1));
      float p3 = __builtin_amdgcn_exp2f(fmaf(sa[kf][3], LOG2E, c1));
      rs += (p0 + p1) + (p2 + p3);
      pk[kf][0] = cvt_pk_bf16(p0, p1);
      pk[kf][1] = cvt_pk_bf16(p2, p3);
    }
    rs += __shfl_xor(rs, 16, 64);
    rs += __shfl_xor(rs, 32, 64);
    l_run += rs;

    // redistribute P across lg-groups: dest(lr,lg) u32[m] =
    //   srcLane(lr, (lg&1)*2 + (m>>1)).pk[2c + (lg>>1)][m&1]
    short8 pa[2];
#pragma unroll
    for (int c = 0; c < 2; ++c) {
      unsigned a0 = __shfl((int)pk[2 * c][0], sl0, 64);
      unsigned b0 = __shfl((int)pk[2 * c + 1][0], sl0, 64);
      unsigned a1 = __shfl((int)pk[2 * c][1], sl0, 64);
      unsigned b1 = __shfl((int)pk[2 * c + 1][1], sl0, 64);
      unsigned a2 = __shfl((int)pk[2 * c][0], sl1, 64);
      unsigned b2 = __shfl((int)pk[2 * c + 1][0], sl1, 64);
      unsigned a3 = __shfl((int)pk[2 * c][1], sl1, 64);
      unsigned b3 = __shfl((int)pk[2 * c + 1][1], sl1, 64);
      uint4v t;
      t[0] = (lg & 2) ? b0 : a0;
      t[1] = (lg & 2) ? b1 : a1;
      t[2] = (lg & 2) ? b2 : a2;
      t[3] = (lg & 2) ? b3 : a3;
      pa[c] = *(short8*)&t;
    }

    // O += P @ V
    __builtin_amdgcn_s_setprio(1);
#pragma unroll
    for (int c = 0; c < 2; ++c)
#pragma unroll
      for (int df = 0; df < 4; ++df) {
        int row = df * 16 + lr;
        short8 bv = *(const short8*)(Vc + row * 64 +
                                     (((c * 4 + lg) ^ (lr & 7)) * 8));
        o[df] = __builtin_amdgcn_mfma_f32_16x16x32_bf16(pa[c], bv, o[df],
                                                        0, 0, 0);
      }
    __builtin_amdgcn_s_setprio(0);
    __syncthreads();  // drains prefetch vmem + guards buffer swap
  }

  // epilogue: lane holds O[q = w*16+lg*4+r][d = df*16+lr]
  if (!partial) {
    float rl[4];
#pragma unroll
    for (int r = 0; r < 4; ++r)
      rl[r] = __builtin_amdgcn_rcpf(__shfl(l_run, lg * 4 + r, 64));
    const size_t outRow0 = bsQ + w * 16 + lg * 4;
#pragma unroll
    for (int df = 0; df < 4; ++df)
#pragma unroll
      for (int r = 0; r < 4; ++r)
        ao[(outRow0 + r) * 1024 + h * 64 + df * 16 + lr] =
            f2bf(o[df][r] * rl[r]);
  } else {
    const int pid = (hb * 16 + (qt - 16)) * 2 + (k0 == 16 ? 1 : 0);
    unsigned short* op = opart + (size_t)pid * 4096;
#pragma unroll
    for (int df = 0; df < 4; ++df)
#pragma unroll
      for (int r = 0; r < 4; ++r)
        op[(w * 16 + lg * 4 + r) * 64 + df * 16 + lr] = f2bf(o[df][r]);
    if (lg == 0) {
      mbuf[pid * 64 + w * 16 + lr] = m_run;
      lbuf[pid * 64 + w * 16 + lr] = l_run;
    }
  }
}

// ------------------------------ combine partials -----------------------------
__global__ void combine_kern(const unsigned short* __restrict__ opart,
                             const float* __restrict__ mbuf,
                             const float* __restrict__ lbuf,
                             unsigned short* __restrict__ ao) {
  const int t = blockIdx.x;         // 0..511
  const int hb = t >> 4;
  const int qtl = t & 15;
  const int qt = 16 + qtl;
  const int b = hb >> 4, h = hb & 15;
  const int pid0 = (hb * 16 + qtl) * 2, pid1 = pid0 + 1;
  const int row = threadIdx.x >> 2;
  const int colg = (threadIdx.x & 3) * 16;

  float m1 = mbuf[pid0 * 64 + row], m2 = mbuf[pid1 * 64 + row];
  float l1 = lbuf[pid0 * 64 + row], l2 = lbuf[pid1 * 64 + row];
  float m = fmaxf(m1, m2);
  float s1 = __builtin_amdgcn_exp2f((m1 - m) * LOG2E);
  float s2 = __builtin_amdgcn_exp2f((m2 - m) * LOG2E);
  float linv = 1.f / fmaf(l1, s1, l2 * s2);
  s1 *= linv; s2 *= linv;

  const unsigned short* O1 = opart + (size_t)pid0 * 4096 + row * 64 + colg;
  const unsigned short* O2 = opart + (size_t)pid1 * 4096 + row * 64 + colg;
  unsigned short* dst =
      ao + ((size_t)b * 2048 + qt * 64 + row) * 1024 + h * 64 + colg;
#pragma unroll
  for (int i = 0; i < 2; ++i) {
    short8 a = *(const short8*)(O1 + i * 8);
    short8 c = *(const short8*)(O2 + i * 8);
    short8 ov;
#pragma unroll
    for (int j = 0; j < 8; ++j)
      ov[j] = (short)f2bf(fmaf(bf2f((unsigned short)a[j]), s1,
                               bf2f((unsigned short)c[j]) * s2));
    *(short8*)(dst + i * 8) = ov;
  }
}

// --------------------------------- launcher ---------------------------------
extern "C" void kernel_launch(void* const* d_in, const int* in_sizes, int n_in,
                              void* d_out, int out_size, void* d_ws,
                              size_t ws_size, hipStream_t stream) {
  const float* k_in = (const float*)d_in[0];  // k == v == q (same x tensor)
  const float* Wk = (const float*)d_in[3];
  const float* Wv = (const float*)d_in[4];
  const float* Wq = (const float*)d_in[5];
  const float* Wo = (const float*)d_in[6];
  const float* pp = (const float*)d_in[7];

  const size_t NX = 4096u * 1024u;
  const size_t NW = 1024u * 1024u;
  unsigned short* ws = (unsigned short*)d_ws;
  unsigned short* xbf = ws;
  unsigned short* wkb = xbf + NX;
  unsigned short* wvb = wkb + NW;
  unsigned short* wqb = wvb + NW;
  unsigned short* wob = wqb + NW;
  unsigned short* khb = wob + NW;
  unsigned short* vtb = khb + NX;
  unsigned short* qhb = vtb + NX;
  unsigned short* aob = qhb + NX;
  unsigned short* opart = aob + NX;          // 1024 tiles x 4096 bf16 = 8 MB
  float* mbuf = (float*)(opart + NX);        // 1024*64 f32
  float* lbuf = mbuf + 1024 * 64;

  (void)in_sizes; (void)n_in; (void)out_size; (void)ws_size;

  f2bf_kern<<<dim3(4096), dim3(256), 0, stream>>>(k_in, xbf, (int)(NX / 4));
  f2bfW_kern<<<dim3(1024, 4), dim3(256), 0, stream>>>(
      Wk, wkb, Wv, wvb, Wq, wqb, Wo, wob);

  proj3_kern<<<dim3(8, 32, 3), dim3(256), 0, stream>>>(
      xbf, wkb, khb, wqb, qhb, wvb, vtb);

  attn_kern<<<dim3(32, 48), dim3(256), 0, stream>>>(qhb, khb, vtb, pp, aob,
                                                    opart, mbuf, lbuf);
  combine_kern<<<dim3(512), dim3(256), 0, stream>>>(opart, mbuf, lbuf, aob);

  gemm_out_kern<<<dim3(8, 32), dim3(256), 0, stream>>>(aob, wob, (float*)d_out);
}